// Round 3
// baseline (1347.077 us; speedup 1.0000x reference)
//
#include <hip/hip_runtime.h>

#define N     512
#define NSP   4          // column stripes per sample
#define SC    128        // columns per stripe
#define EPS   1e-4f

// ---- fallback (previous pipeline) LDS layout ----
#define MROW  65
#define LDS_U   (512 * MROW + 512 + 128 * 33 + 128 + 64)
#define LDS_BYTES (LDS_U * 4)

// ---- f16 helpers ----
union U32H { unsigned int u; _Float16 h[2]; };
__device__ inline float h_lo(unsigned int x){ U32H t; t.u = x; return (float)t.h[0]; }
__device__ inline float h_hi(unsigned int x){ U32H t; t.u = x; return (float)t.h[1]; }
__device__ inline unsigned int h_pk(float a, float b){ U32H t; t.h[0]=(_Float16)a; t.h[1]=(_Float16)b; return t.u; }

typedef _Float16 half2v __attribute__((ext_vector_type(2)));
#if __has_builtin(__builtin_amdgcn_fdot2)
__device__ inline float dot2(unsigned int m, unsigned int v, float c){
    return __builtin_amdgcn_fdot2(__builtin_bit_cast(half2v, m), __builtin_bit_cast(half2v, v), c, false);
}
#else
__device__ inline float dot2(unsigned int m, unsigned int v, float c){
    return c + h_lo(m)*h_lo(v) + h_hi(m)*h_hi(v);
}
#endif

typedef unsigned int uint4v __attribute__((ext_vector_type(4)));

// ============================================================================
// Fused cooperative kernel, take 3.
// Rounds 1-2 failure mode: cg::grid_group::sync() is an outlined call
// (__ockl_grid_sync) -> all 64 VGPRs of m live across it get caller-save
// spilled to scratch 5x (VGPR_Count=64 both rounds, +220 MB HBM each way).
// Fix: fully-inlined hand-rolled grid barrier (threadfence + device-scope
// atomic arrive + acquire spin by t0). No calls anywhere in the kernel body.
// m is an array of ext_vector uint4 (pattern proven register-resident).
// ============================================================================

// inlined grid barrier; counter pre-zeroed per launch via hipMemsetAsync
#define GRID_SYNC() do {                                                      \
    __syncthreads();                                                          \
    __threadfence();                        /* release: publish rp writes */  \
    ++phase;                                                                  \
    if (t == 0) {                                                             \
        __hip_atomic_fetch_add(bar, 1u, __ATOMIC_RELEASE,                     \
                               __HIP_MEMORY_SCOPE_AGENT);                     \
        while (__hip_atomic_load(bar, __ATOMIC_ACQUIRE,                       \
                                 __HIP_MEMORY_SCOPE_AGENT)                    \
               < (unsigned int)(phase * nblk)) {                              \
            __builtin_amdgcn_s_sleep(1);                                      \
        }                                                                     \
    }                                                                         \
    __syncthreads();                                                          \
    __threadfence();                        /* acquire: invalidate L1/L2 */   \
} while (0)

// col-sum reduce across 32 row-partitions -> vf = 1/colsum, vpk = packed f16
#define COL_REDUCE() do {                                                     \
    _Pragma("unroll")                                                         \
    for (int k_ = 0; k_ < 8; ++k_) red[(8*j + k_)*33 + part] = acc[k_];       \
    __syncthreads();                                                          \
    if (t < 128) {                                                            \
        float s_ = 0.f;                                                       \
        _Pragma("unroll")                                                     \
        for (int p_ = 0; p_ < 32; ++p_) s_ += red[t*33 + p_];                 \
        vf[t] = (c0 + t < n) ? 1.f / s_ : 0.f;                                \
    }                                                                         \
    __syncthreads();                                                          \
    if (t < 64) vpk[t] = h_pk(vf[2*t], vf[2*t+1]);                            \
    __syncthreads();                                                          \
} while (0)

// row partials: dot(m-row, v) per owned row -> LDS -> sum over 16 j-lanes
#define ROW_PART(RPOUT) do {                                                  \
    const unsigned int vp0_ = vpk[4*j+0], vp1_ = vpk[4*j+1];                  \
    const unsigned int vp2_ = vpk[4*j+2], vp3_ = vpk[4*j+3];                  \
    _Pragma("unroll")                                                         \
    for (int it_ = 0; it_ < 16; ++it_) {                                      \
        float p_ = dot2(m[it_][0], vp0_, 0.f);                                \
        p_ = dot2(m[it_][1], vp1_, p_);                                       \
        p_ = dot2(m[it_][2], vp2_, p_);                                       \
        p_ = dot2(m[it_][3], vp3_, p_);                                       \
        rowred[(it_*32 + part)*17 + j] = p_;                                  \
    }                                                                         \
    __syncthreads();                                                          \
    {                                                                         \
        float s_ = 0.f;                                                       \
        _Pragma("unroll")                                                     \
        for (int q_ = 0; q_ < 16; ++q_) s_ += rowred[t*17 + q_];              \
        (RPOUT)[rpOff + t] = s_;                                              \
    }                                                                         \
    __syncthreads();                                                          \
} while (0)

__global__ __launch_bounds__(512, 4)
void k_fused(const float* __restrict__ A, const int* __restrict__ nrows,
             float* __restrict__ rpA, float* __restrict__ rpB,
             float* __restrict__ out, unsigned int* __restrict__ bar,
             int nblk) {
    __shared__ float red[128*33];        // 16.5 KiB
    __shared__ float rowred[512*17];     // 34.0 KiB
    __shared__ float uu[512];
    __shared__ float vf[128];
    __shared__ unsigned int vpk[64];     // total ~53.3 KiB -> 2 blocks/CU

    const int b = blockIdx.y, sp = blockIdx.x, c0 = sp * SC;
    const int n = nrows[b];
    const int t = threadIdx.x;
    const int l = t & 63;
    const int j = l & 15;
    const int part = (t >> 6) * 4 + (l >> 4);   // 0..31
    const size_t baseA = (size_t)b * N * N;
    const int cb = c0 + 8*j;
    const size_t rpOff = ((size_t)b * NSP + sp) * N;
    const size_t rpB0  = (size_t)b * NSP * N;
    int phase = 0;

    uint4v m[16];            // must stay in VGPRs: constant indices only
    float acc[8];

    // ---- load A once -> masked f16 in registers; pass-0 col sums (u == 1) ----
    {
        bool cok0 = (cb+0) < n, cok1 = (cb+1) < n, cok2 = (cb+2) < n, cok3 = (cb+3) < n;
        bool cok4 = (cb+4) < n, cok5 = (cb+5) < n, cok6 = (cb+6) < n, cok7 = (cb+7) < n;
#pragma unroll
        for (int k = 0; k < 8; ++k) acc[k] = 0.f;
#pragma unroll
        for (int it = 0; it < 16; ++it) {
            const int r = it*32 + part;
            const float4* p = (const float4*)(A + baseA + (size_t)r*N + cb);
            float4 a0 = p[0], a1 = p[1];
            const bool rok = r < n;
            float e0 = (rok & cok0) ? a0.x + EPS : 0.f;
            float e1 = (rok & cok1) ? a0.y + EPS : 0.f;
            float e2 = (rok & cok2) ? a0.z + EPS : 0.f;
            float e3 = (rok & cok3) ? a0.w + EPS : 0.f;
            float e4 = (rok & cok4) ? a1.x + EPS : 0.f;
            float e5 = (rok & cok5) ? a1.y + EPS : 0.f;
            float e6 = (rok & cok6) ? a1.z + EPS : 0.f;
            float e7 = (rok & cok7) ? a1.w + EPS : 0.f;
            acc[0] += e0; acc[1] += e1; acc[2] += e2; acc[3] += e3;
            acc[4] += e4; acc[5] += e5; acc[6] += e6; acc[7] += e7;
            m[it][0] = h_pk(e0, e1);
            m[it][1] = h_pk(e2, e3);
            m[it][2] = h_pk(e4, e5);
            m[it][3] = h_pk(e6, e7);
        }
    }
    COL_REDUCE();            // v0
    ROW_PART(rpA);           // rp1
    GRID_SYNC();

    // ---- passes 1..4: u = 1/sum(rp), col-normalize, next row partials ----
    float* rIn = rpA; float* rOut = rpB;
    for (int ps = 0; ps < 4; ++ps) {
        {
            float s = rIn[rpB0 + 0*N + t] + rIn[rpB0 + 1*N + t]
                    + rIn[rpB0 + 2*N + t] + rIn[rpB0 + 3*N + t];
            uu[t] = (t < n) ? 1.f / s : 0.f;
        }
        __syncthreads();
#pragma unroll
        for (int k = 0; k < 8; ++k) acc[k] = 0.f;
#pragma unroll
        for (int it = 0; it < 16; ++it) {
            const float ur = uu[it*32 + part];
            acc[0] += ur * h_lo(m[it][0]);
            acc[1] += ur * h_hi(m[it][0]);
            acc[2] += ur * h_lo(m[it][1]);
            acc[3] += ur * h_hi(m[it][1]);
            acc[4] += ur * h_lo(m[it][2]);
            acc[5] += ur * h_hi(m[it][2]);
            acc[6] += ur * h_lo(m[it][3]);
            acc[7] += ur * h_hi(m[it][3]);
        }
        COL_REDUCE();        // v2 / v4 / v6 / v8
        ROW_PART(rOut);      // rp3 / rp5 / rp7 / rp9
        GRID_SYNC();
        float* tmp = rIn; rIn = rOut; rOut = tmp;
    }
    // after 4 swaps: rIn holds rp9; vf holds v8

    // ---- epilogue from registers: out = m * u9[r] * v8[c] ----
    {
        float s = rIn[rpB0 + 0*N + t] + rIn[rpB0 + 1*N + t]
                + rIn[rpB0 + 2*N + t] + rIn[rpB0 + 3*N + t];
        uu[t] = (t < n) ? 1.f / s : 0.f;
    }
    __syncthreads();
    const float v0 = vf[8*j+0], v1 = vf[8*j+1], v2 = vf[8*j+2], v3 = vf[8*j+3];
    const float v4 = vf[8*j+4], v5 = vf[8*j+5], v6 = vf[8*j+6], v7 = vf[8*j+7];
#pragma unroll
    for (int it = 0; it < 16; ++it) {
        const int r = it*32 + part;
        const float ur = uu[r];
        float4 o0, o1;
        o0.x = h_lo(m[it][0]) * ur * v0;
        o0.y = h_hi(m[it][0]) * ur * v1;
        o0.z = h_lo(m[it][1]) * ur * v2;
        o0.w = h_hi(m[it][1]) * ur * v3;
        o1.x = h_lo(m[it][2]) * ur * v4;
        o1.y = h_hi(m[it][2]) * ur * v5;
        o1.z = h_lo(m[it][3]) * ur * v6;
        o1.w = h_hi(m[it][3]) * ur * v7;
        float4* q = (float4*)(out + baseA + (size_t)r*N + cb);
        q[0] = o0; q[1] = o1;
    }
}

// ============================================================================
// Fallback: verified 6-kernel pipeline (runs if cooperative launch or the
// barrier-counter memset is rejected).
// ============================================================================

__device__ inline void pass_tail(unsigned int* M2, float* red, float* vf, unsigned int* vpk,
                                 const float acc[8], int t, int part, int j, int c0, int n,
                                 int b, int sp, float* __restrict__ rp_out,
                                 float* __restrict__ vf_out) {
#pragma unroll
    for (int k = 0; k < 8; ++k) red[(8*j + k)*33 + part] = acc[k];
    __syncthreads();
    if (t < 128) {
        float s = 0.f;
#pragma unroll
        for (int p = 0; p < 32; ++p) s += red[t*33 + p];
        float v = (c0 + t < n) ? 1.f / s : 0.f;
        vf[t] = v;
        if (vf_out) vf_out[b*N + c0 + t] = v;
    }
    __syncthreads();
    if (t < 64) vpk[t] = h_pk(vf[2*t], vf[2*t+1]);
    __syncthreads();
    float p = 0.f;
    const unsigned int* row = M2 + t * MROW;
#pragma unroll
    for (int q = 0; q < 64; ++q) p = dot2(row[q], vpk[q], p);
    rp_out[((size_t)b*NSP + sp)*N + t] = p;
}

__global__ __launch_bounds__(512)
void k_pass0(const float* __restrict__ A, const int* __restrict__ nrows,
             unsigned int* __restrict__ Abf, float* __restrict__ rp_out) {
    extern __shared__ unsigned int lds[];
    unsigned int* M2 = lds;
    float* uu = (float*)(lds + 512*MROW);
    float* red = uu + 512;
    float* vf  = red + 128*33;
    unsigned int* vpk = (unsigned int*)(vf + 128);

    const int b = blockIdx.y, sp = blockIdx.x, c0 = sp * SC;
    const int n = nrows[b];
    const int t = threadIdx.x;
    const int w = t >> 6, l = t & 63;
    const int j = l & 15, rg = l >> 4;
    const size_t baseA = (size_t)b * N * N;
    const size_t baseH = (size_t)b * N * (N/2);
    const int cb = c0 + 8*j;

    bool cok[8];
#pragma unroll
    for (int k = 0; k < 8; ++k) cok[k] = (cb + k) < n;

    float acc[8] = {0,0,0,0,0,0,0,0};
    for (int it = 0; it < 16; ++it) {
        int r = it*32 + w*4 + rg;
        const float4* p = (const float4*)(A + baseA + (size_t)r*N + cb);
        float4 a0 = p[0], a1 = p[1];
        bool rok = r < n;
        float e[8];
        e[0] = (rok && cok[0]) ? a0.x + EPS : 0.f;
        e[1] = (rok && cok[1]) ? a0.y + EPS : 0.f;
        e[2] = (rok && cok[2]) ? a0.z + EPS : 0.f;
        e[3] = (rok && cok[3]) ? a0.w + EPS : 0.f;
        e[4] = (rok && cok[4]) ? a1.x + EPS : 0.f;
        e[5] = (rok && cok[5]) ? a1.y + EPS : 0.f;
        e[6] = (rok && cok[6]) ? a1.z + EPS : 0.f;
        e[7] = (rok && cok[7]) ? a1.w + EPS : 0.f;
#pragma unroll
        for (int k = 0; k < 8; ++k) acc[k] += e[k];
        uint4 q;
        q.x = h_pk(e[0], e[1]); q.y = h_pk(e[2], e[3]);
        q.z = h_pk(e[4], e[5]); q.w = h_pk(e[6], e[7]);
        *(uint4*)(Abf + baseH + (size_t)r*(N/2) + c0/2 + 4*j) = q;
        unsigned int* dst = M2 + r*MROW + 4*j;
        dst[0] = q.x; dst[1] = q.y; dst[2] = q.z; dst[3] = q.w;
    }
    (void)uu;
    pass_tail(M2, red, vf, vpk, acc, t, w*4 + rg, j, c0, n, b, sp, rp_out, nullptr);
}

__global__ __launch_bounds__(512)
void k_passN(const unsigned int* __restrict__ Abf, const int* __restrict__ nrows,
             const float* __restrict__ rp_in, float* __restrict__ rp_out,
             float* __restrict__ vf_out) {
    extern __shared__ unsigned int lds[];
    unsigned int* M2 = lds;
    float* uu = (float*)(lds + 512*MROW);
    float* red = uu + 512;
    float* vf  = red + 128*33;
    unsigned int* vpk = (unsigned int*)(vf + 128);

    const int b = blockIdx.y, sp = blockIdx.x, c0 = sp * SC;
    const int n = nrows[b];
    const int t = threadIdx.x;
    const int w = t >> 6, l = t & 63;
    const int j = l & 15, rg = l >> 4;
    const size_t baseH = (size_t)b * N * (N/2);

    {
        float s = rp_in[((size_t)b*NSP + 0)*N + t]
                + rp_in[((size_t)b*NSP + 1)*N + t]
                + rp_in[((size_t)b*NSP + 2)*N + t]
                + rp_in[((size_t)b*NSP + 3)*N + t];
        uu[t] = (t < n) ? 1.f / s : 0.f;
    }
    __syncthreads();

    float acc[8] = {0,0,0,0,0,0,0,0};
    for (int it = 0; it < 16; ++it) {
        int r = it*32 + w*4 + rg;
        uint4 q = *(const uint4*)(Abf + baseH + (size_t)r*(N/2) + c0/2 + 4*j);
        float ur = uu[r];
        acc[0] += ur * h_lo(q.x); acc[1] += ur * h_hi(q.x);
        acc[2] += ur * h_lo(q.y); acc[3] += ur * h_hi(q.y);
        acc[4] += ur * h_lo(q.z); acc[5] += ur * h_hi(q.z);
        acc[6] += ur * h_lo(q.w); acc[7] += ur * h_hi(q.w);
        unsigned int* dst = M2 + r*MROW + 4*j;
        dst[0] = q.x; dst[1] = q.y; dst[2] = q.z; dst[3] = q.w;
    }
    __syncthreads();
    pass_tail(M2, red, vf, vpk, acc, t, w*4 + rg, j, c0, n, b, sp, rp_out, vf_out);
}

__global__ __launch_bounds__(512)
void k_epi(const float* __restrict__ A, const int* __restrict__ nrows,
           const float* __restrict__ rp9, const float* __restrict__ vf8,
           float* __restrict__ out) {
    const int b = blockIdx.y;
    const int n = nrows[b];
    const int t = threadIdx.x;
    const int r = blockIdx.x*4 + (t >> 7);
    const int c = (t & 127) * 4;
    float s = rp9[((size_t)b*NSP + 0)*N + r]
            + rp9[((size_t)b*NSP + 1)*N + r]
            + rp9[((size_t)b*NSP + 2)*N + r]
            + rp9[((size_t)b*NSP + 3)*N + r];
    float ur = (r < n) ? 1.f / s : 0.f;
    float4 v = *(const float4*)(vf8 + b*N + c);
    const size_t off = (size_t)b*N*N + (size_t)r*N + c;
    float4 a = *(const float4*)(A + off);
    float4 o;
    o.x = (a.x + EPS) * ur * v.x;
    o.y = (a.y + EPS) * ur * v.y;
    o.z = (a.z + EPS) * ur * v.z;
    o.w = (a.w + EPS) * ur * v.w;
    *(float4*)(out + off) = o;
}

extern "C" void kernel_launch(void* const* d_in, const int* in_sizes, int n_in,
                              void* d_out, int out_size, void* d_ws, size_t ws_size,
                              hipStream_t stream) {
    const float* A     = (const float*)d_in[0];
    const int*   nrows = (const int*)d_in[1];
    float*       out   = (float*)d_out;
    const int    B     = in_sizes[1];   // 128

    float* rpA = (float*)d_ws;
    float* rpB = rpA + (size_t)B * NSP * N;
    float* vf8 = rpB + (size_t)B * NSP * N;
    // barrier counter: 256B-aligned slot well past the rp/vf8 region (4 MiB).
    unsigned int* bar = (unsigned int*)((char*)d_ws + (4u << 20));
    int nblk = NSP * B;

    // ---- preferred path: single cooperative kernel, 2 blocks/CU resident ----
    do {
        if (hipMemsetAsync(bar, 0, 64, stream) != hipSuccess) break;
        void* args[] = { (void*)&A, (void*)&nrows, (void*)&rpA, (void*)&rpB,
                         (void*)&out, (void*)&bar, (void*)&nblk };
        hipError_t err = hipLaunchCooperativeKernel(
            reinterpret_cast<const void*>(&k_fused),
            dim3(NSP, B), dim3(512), args, 0, stream);
        if (err == hipSuccess) return;
    } while (0);

    // ---- fallback: previous verified multi-kernel pipeline ----
    size_t head = ((size_t)2*B*NSP*N + (size_t)B*N) * sizeof(float);
    size_t abf_bytes = (size_t)B * N * (N/2) * sizeof(unsigned int);
    unsigned int* Abf = (ws_size >= head + abf_bytes)
                      ? (unsigned int*)((char*)d_ws + head)
                      : (unsigned int*)d_out;

    hipFuncSetAttribute(reinterpret_cast<const void*>(k_pass0),
                        hipFuncAttributeMaxDynamicSharedMemorySize, LDS_BYTES);
    hipFuncSetAttribute(reinterpret_cast<const void*>(k_passN),
                        hipFuncAttributeMaxDynamicSharedMemorySize, LDS_BYTES);

    dim3 g(NSP, B);
    k_pass0<<<g, 512, LDS_BYTES, stream>>>(A, nrows, Abf, rpA);
    k_passN<<<g, 512, LDS_BYTES, stream>>>(Abf, nrows, rpA, rpB, nullptr);
    k_passN<<<g, 512, LDS_BYTES, stream>>>(Abf, nrows, rpB, rpA, nullptr);
    k_passN<<<g, 512, LDS_BYTES, stream>>>(Abf, nrows, rpA, rpB, nullptr);
    k_passN<<<g, 512, LDS_BYTES, stream>>>(Abf, nrows, rpB, rpA, vf8);
    k_epi<<<dim3(N/4, B), 512, 0, stream>>>(A, nrows, rpA, vf8, out);
}

// Round 5
// 914.921 us; speedup vs baseline: 1.4723x; 1.4723x over previous
//
#include <hip/hip_runtime.h>

#define N     512
#define NSP   4          // column stripes per sample
#define SC    128        // columns per stripe
#define EPS   1e-4f

// ---- fallback (previous pipeline) LDS layout ----
#define MROW  65
#define LDS_U   (512 * MROW + 512 + 128 * 33 + 128 + 64)
#define LDS_BYTES (LDS_U * 4)

// ---- f16 helpers ----
union U32H { unsigned int u; _Float16 h[2]; };
__device__ inline float h_lo(unsigned int x){ U32H t; t.u = x; return (float)t.h[0]; }
__device__ inline float h_hi(unsigned int x){ U32H t; t.u = x; return (float)t.h[1]; }
__device__ inline unsigned int h_pk(float a, float b){ U32H t; t.h[0]=(_Float16)a; t.h[1]=(_Float16)b; return t.u; }

typedef _Float16 half2v __attribute__((ext_vector_type(2)));
#if __has_builtin(__builtin_amdgcn_fdot2)
__device__ inline float dot2(unsigned int m, unsigned int v, float c){
    return __builtin_amdgcn_fdot2(__builtin_bit_cast(half2v, m), __builtin_bit_cast(half2v, v), c, false);
}
#else
__device__ inline float dot2(unsigned int m, unsigned int v, float c){
    return c + h_lo(m)*h_lo(v) + h_hi(m)*h_hi(v);
}
#endif

typedef unsigned int uint4v __attribute__((ext_vector_type(4)));

// ============================================================================
// Fused cooperative kernel, take 5.
// VGPR-cap theory (live): __launch_bounds__ 2nd arg read as blocks/CU ->
// (512,4)=8 waves/SIMD -> 64-reg cap (matches rounds 1-3 exactly; m[16]
// alone needs 64 -> forced scratch). (512,2) -> 4 waves/SIMD -> 128 cap.
// Round-4 hang root cause: RELAXED *load* poll can hit the spinner's own
// XCD L2 (not cross-coherent) forever -> deadlock. Fix: poll with an RMW
// (fetch_add 0) which always executes at the coherent point, plus s_sleep.
// Barrier scope shrunk grid -> per-sample: row sums only cross the 4
// stripe-blocks of one b, so each sync waits on 3 siblings, not 511.
// ============================================================================

// per-sample 4-block barrier; counters zeroed per launch via hipMemsetAsync
#define SAMPLE_SYNC() do {                                                    \
    __syncthreads();                                                          \
    __threadfence();                      /* release: publish rp stores */    \
    ++phase;                                                                  \
    if (t == 0) {                                                             \
        __hip_atomic_fetch_add(barb, 1u, __ATOMIC_RELEASE,                    \
                               __HIP_MEMORY_SCOPE_AGENT);                     \
        const unsigned int tgt_ = (unsigned int)(phase * NSP);                \
        while (__hip_atomic_fetch_add(barb, 0u, __ATOMIC_RELAXED,             \
                                      __HIP_MEMORY_SCOPE_AGENT) < tgt_) {     \
            __builtin_amdgcn_s_sleep(8);                                      \
        }                                                                     \
    }                                                                         \
    __syncthreads();                                                          \
    __threadfence();                      /* acquire side, once */            \
} while (0)

// col-sum reduce across 32 row-partitions -> vf = 1/colsum, vpk = packed f16
#define COL_REDUCE() do {                                                     \
    _Pragma("unroll")                                                         \
    for (int k_ = 0; k_ < 8; ++k_) red[(8*j + k_)*33 + part] = acc[k_];       \
    __syncthreads();                                                          \
    if (t < 128) {                                                            \
        float s_ = 0.f;                                                       \
        _Pragma("unroll")                                                     \
        for (int p_ = 0; p_ < 32; ++p_) s_ += red[t*33 + p_];                 \
        vf[t] = (c0 + t < n) ? 1.f / s_ : 0.f;                                \
    }                                                                         \
    __syncthreads();                                                          \
    if (t < 64) vpk[t] = h_pk(vf[2*t], vf[2*t+1]);                            \
    __syncthreads();                                                          \
} while (0)

// row partials: dot(m-row, v) per owned row -> LDS -> sum over 16 j-lanes
#define ROW_PART(RPOUT) do {                                                  \
    const unsigned int vp0_ = vpk[4*j+0], vp1_ = vpk[4*j+1];                  \
    const unsigned int vp2_ = vpk[4*j+2], vp3_ = vpk[4*j+3];                  \
    _Pragma("unroll")                                                         \
    for (int it_ = 0; it_ < 16; ++it_) {                                      \
        float p_ = dot2(m[it_][0], vp0_, 0.f);                                \
        p_ = dot2(m[it_][1], vp1_, p_);                                       \
        p_ = dot2(m[it_][2], vp2_, p_);                                       \
        p_ = dot2(m[it_][3], vp3_, p_);                                       \
        rowred[(it_*32 + part)*17 + j] = p_;                                  \
    }                                                                         \
    __syncthreads();                                                          \
    {                                                                         \
        float s_ = 0.f;                                                       \
        _Pragma("unroll")                                                     \
        for (int q_ = 0; q_ < 16; ++q_) s_ += rowred[t*17 + q_];              \
        (RPOUT)[rpOff + t] = s_;                                              \
    }                                                                         \
    __syncthreads();                                                          \
} while (0)

__global__ __launch_bounds__(512, 2)
void k_fused(const float* __restrict__ A, const int* __restrict__ nrows,
             float* __restrict__ rpA, float* __restrict__ rpB,
             float* __restrict__ out, unsigned int* __restrict__ bar) {
    __shared__ float red[128*33];        // 16.5 KiB
    __shared__ float rowred[512*17];     // 34.0 KiB
    __shared__ float uu[512];
    __shared__ float vf[128];
    __shared__ unsigned int vpk[64];     // total ~53.3 KiB -> 2 blocks/CU

    const int b = blockIdx.y, sp = blockIdx.x, c0 = sp * SC;
    const int n = nrows[b];
    const int t = threadIdx.x;
    const int l = t & 63;
    const int j = l & 15;
    const int part = (t >> 6) * 4 + (l >> 4);   // 0..31
    const size_t baseA = (size_t)b * N * N;
    const int cb = c0 + 8*j;
    const size_t rpOff = ((size_t)b * NSP + sp) * N;
    const size_t rpB0  = (size_t)b * NSP * N;
    unsigned int* barb = bar + (size_t)b * 32;  // one cacheline per sample
    int phase = 0;

    uint4v m[16];            // must stay in VGPRs: constant indices only
    float acc[8];

    // ---- load A once -> masked f16 in registers; pass-0 col sums (u == 1) ----
    {
        bool cok0 = (cb+0) < n, cok1 = (cb+1) < n, cok2 = (cb+2) < n, cok3 = (cb+3) < n;
        bool cok4 = (cb+4) < n, cok5 = (cb+5) < n, cok6 = (cb+6) < n, cok7 = (cb+7) < n;
#pragma unroll
        for (int k = 0; k < 8; ++k) acc[k] = 0.f;
#pragma unroll
        for (int it = 0; it < 16; ++it) {
            const int r = it*32 + part;
            const float4* p = (const float4*)(A + baseA + (size_t)r*N + cb);
            float4 a0 = p[0], a1 = p[1];
            const bool rok = r < n;
            float e0 = (rok & cok0) ? a0.x + EPS : 0.f;
            float e1 = (rok & cok1) ? a0.y + EPS : 0.f;
            float e2 = (rok & cok2) ? a0.z + EPS : 0.f;
            float e3 = (rok & cok3) ? a0.w + EPS : 0.f;
            float e4 = (rok & cok4) ? a1.x + EPS : 0.f;
            float e5 = (rok & cok5) ? a1.y + EPS : 0.f;
            float e6 = (rok & cok6) ? a1.z + EPS : 0.f;
            float e7 = (rok & cok7) ? a1.w + EPS : 0.f;
            acc[0] += e0; acc[1] += e1; acc[2] += e2; acc[3] += e3;
            acc[4] += e4; acc[5] += e5; acc[6] += e6; acc[7] += e7;
            m[it][0] = h_pk(e0, e1);
            m[it][1] = h_pk(e2, e3);
            m[it][2] = h_pk(e4, e5);
            m[it][3] = h_pk(e6, e7);
        }
    }
    COL_REDUCE();            // v0
    ROW_PART(rpA);           // rp1
    SAMPLE_SYNC();

    // ---- passes 1..4: u = 1/sum(rp), col-normalize, next row partials ----
    float* rIn = rpA; float* rOut = rpB;
    for (int ps = 0; ps < 4; ++ps) {
        {
            float s = rIn[rpB0 + 0*N + t] + rIn[rpB0 + 1*N + t]
                    + rIn[rpB0 + 2*N + t] + rIn[rpB0 + 3*N + t];
            uu[t] = (t < n) ? 1.f / s : 0.f;
        }
        __syncthreads();
#pragma unroll
        for (int k = 0; k < 8; ++k) acc[k] = 0.f;
#pragma unroll
        for (int it = 0; it < 16; ++it) {
            const float ur = uu[it*32 + part];
            acc[0] += ur * h_lo(m[it][0]);
            acc[1] += ur * h_hi(m[it][0]);
            acc[2] += ur * h_lo(m[it][1]);
            acc[3] += ur * h_hi(m[it][1]);
            acc[4] += ur * h_lo(m[it][2]);
            acc[5] += ur * h_hi(m[it][2]);
            acc[6] += ur * h_lo(m[it][3]);
            acc[7] += ur * h_hi(m[it][3]);
        }
        COL_REDUCE();        // v2 / v4 / v6 / v8
        ROW_PART(rOut);      // rp3 / rp5 / rp7 / rp9
        SAMPLE_SYNC();
        float* tmp = rIn; rIn = rOut; rOut = tmp;
    }
    // after 4 swaps: rIn holds rp9; vf holds v8

    // ---- epilogue from registers: out = m * u9[r] * v8[c] ----
    {
        float s = rIn[rpB0 + 0*N + t] + rIn[rpB0 + 1*N + t]
                + rIn[rpB0 + 2*N + t] + rIn[rpB0 + 3*N + t];
        uu[t] = (t < n) ? 1.f / s : 0.f;
    }
    __syncthreads();
    const float v0 = vf[8*j+0], v1 = vf[8*j+1], v2 = vf[8*j+2], v3 = vf[8*j+3];
    const float v4 = vf[8*j+4], v5 = vf[8*j+5], v6 = vf[8*j+6], v7 = vf[8*j+7];
#pragma unroll
    for (int it = 0; it < 16; ++it) {
        const int r = it*32 + part;
        const float ur = uu[r];
        float4 o0, o1;
        o0.x = h_lo(m[it][0]) * ur * v0;
        o0.y = h_hi(m[it][0]) * ur * v1;
        o0.z = h_lo(m[it][1]) * ur * v2;
        o0.w = h_hi(m[it][1]) * ur * v3;
        o1.x = h_lo(m[it][2]) * ur * v4;
        o1.y = h_hi(m[it][2]) * ur * v5;
        o1.z = h_lo(m[it][3]) * ur * v6;
        o1.w = h_hi(m[it][3]) * ur * v7;
        float4* q = (float4*)(out + baseA + (size_t)r*N + cb);
        q[0] = o0; q[1] = o1;
    }
}

// ============================================================================
// Fallback: verified 6-kernel pipeline (runs if cooperative launch or the
// barrier-counter memset is rejected).
// ============================================================================

__device__ inline void pass_tail(unsigned int* M2, float* red, float* vf, unsigned int* vpk,
                                 const float acc[8], int t, int part, int j, int c0, int n,
                                 int b, int sp, float* __restrict__ rp_out,
                                 float* __restrict__ vf_out) {
#pragma unroll
    for (int k = 0; k < 8; ++k) red[(8*j + k)*33 + part] = acc[k];
    __syncthreads();
    if (t < 128) {
        float s = 0.f;
#pragma unroll
        for (int p = 0; p < 32; ++p) s += red[t*33 + p];
        float v = (c0 + t < n) ? 1.f / s : 0.f;
        vf[t] = v;
        if (vf_out) vf_out[b*N + c0 + t] = v;
    }
    __syncthreads();
    if (t < 64) vpk[t] = h_pk(vf[2*t], vf[2*t+1]);
    __syncthreads();
    float p = 0.f;
    const unsigned int* row = M2 + t * MROW;
#pragma unroll
    for (int q = 0; q < 64; ++q) p = dot2(row[q], vpk[q], p);
    rp_out[((size_t)b*NSP + sp)*N + t] = p;
}

__global__ __launch_bounds__(512)
void k_pass0(const float* __restrict__ A, const int* __restrict__ nrows,
             unsigned int* __restrict__ Abf, float* __restrict__ rp_out) {
    extern __shared__ unsigned int lds[];
    unsigned int* M2 = lds;
    float* uu = (float*)(lds + 512*MROW);
    float* red = uu + 512;
    float* vf  = red + 128*33;
    unsigned int* vpk = (unsigned int*)(vf + 128);

    const int b = blockIdx.y, sp = blockIdx.x, c0 = sp * SC;
    const int n = nrows[b];
    const int t = threadIdx.x;
    const int w = t >> 6, l = t & 63;
    const int j = l & 15, rg = l >> 4;
    const size_t baseA = (size_t)b * N * N;
    const size_t baseH = (size_t)b * N * (N/2);
    const int cb = c0 + 8*j;

    bool cok[8];
#pragma unroll
    for (int k = 0; k < 8; ++k) cok[k] = (cb + k) < n;

    float acc[8] = {0,0,0,0,0,0,0,0};
    for (int it = 0; it < 16; ++it) {
        int r = it*32 + w*4 + rg;
        const float4* p = (const float4*)(A + baseA + (size_t)r*N + cb);
        float4 a0 = p[0], a1 = p[1];
        bool rok = r < n;
        float e[8];
        e[0] = (rok && cok[0]) ? a0.x + EPS : 0.f;
        e[1] = (rok && cok[1]) ? a0.y + EPS : 0.f;
        e[2] = (rok && cok[2]) ? a0.z + EPS : 0.f;
        e[3] = (rok && cok[3]) ? a0.w + EPS : 0.f;
        e[4] = (rok && cok[4]) ? a1.x + EPS : 0.f;
        e[5] = (rok && cok[5]) ? a1.y + EPS : 0.f;
        e[6] = (rok && cok[6]) ? a1.z + EPS : 0.f;
        e[7] = (rok && cok[7]) ? a1.w + EPS : 0.f;
#pragma unroll
        for (int k = 0; k < 8; ++k) acc[k] += e[k];
        uint4 q;
        q.x = h_pk(e[0], e[1]); q.y = h_pk(e[2], e[3]);
        q.z = h_pk(e[4], e[5]); q.w = h_pk(e[6], e[7]);
        *(uint4*)(Abf + baseH + (size_t)r*(N/2) + c0/2 + 4*j) = q;
        unsigned int* dst = M2 + r*MROW + 4*j;
        dst[0] = q.x; dst[1] = q.y; dst[2] = q.z; dst[3] = q.w;
    }
    (void)uu;
    pass_tail(M2, red, vf, vpk, acc, t, w*4 + rg, j, c0, n, b, sp, rp_out, nullptr);
}

__global__ __launch_bounds__(512)
void k_passN(const unsigned int* __restrict__ Abf, const int* __restrict__ nrows,
             const float* __restrict__ rp_in, float* __restrict__ rp_out,
             float* __restrict__ vf_out) {
    extern __shared__ unsigned int lds[];
    unsigned int* M2 = lds;
    float* uu = (float*)(lds + 512*MROW);
    float* red = uu + 512;
    float* vf  = red + 128*33;
    unsigned int* vpk = (unsigned int*)(vf + 128);

    const int b = blockIdx.y, sp = blockIdx.x, c0 = sp * SC;
    const int n = nrows[b];
    const int t = threadIdx.x;
    const int w = t >> 6, l = t & 63;
    const int j = l & 15, rg = l >> 4;
    const size_t baseH = (size_t)b * N * (N/2);

    {
        float s = rp_in[((size_t)b*NSP + 0)*N + t]
                + rp_in[((size_t)b*NSP + 1)*N + t]
                + rp_in[((size_t)b*NSP + 2)*N + t]
                + rp_in[((size_t)b*NSP + 3)*N + t];
        uu[t] = (t < n) ? 1.f / s : 0.f;
    }
    __syncthreads();

    float acc[8] = {0,0,0,0,0,0,0,0};
    for (int it = 0; it < 16; ++it) {
        int r = it*32 + w*4 + rg;
        uint4 q = *(const uint4*)(Abf + baseH + (size_t)r*(N/2) + c0/2 + 4*j);
        float ur = uu[r];
        acc[0] += ur * h_lo(q.x); acc[1] += ur * h_hi(q.x);
        acc[2] += ur * h_lo(q.y); acc[3] += ur * h_hi(q.y);
        acc[4] += ur * h_lo(q.z); acc[5] += ur * h_hi(q.z);
        acc[6] += ur * h_lo(q.w); acc[7] += ur * h_hi(q.w);
        unsigned int* dst = M2 + r*MROW + 4*j;
        dst[0] = q.x; dst[1] = q.y; dst[2] = q.z; dst[3] = q.w;
    }
    __syncthreads();
    pass_tail(M2, red, vf, vpk, acc, t, w*4 + rg, j, c0, n, b, sp, rp_out, vf_out);
}

__global__ __launch_bounds__(512)
void k_epi(const float* __restrict__ A, const int* __restrict__ nrows,
           const float* __restrict__ rp9, const float* __restrict__ vf8,
           float* __restrict__ out) {
    const int b = blockIdx.y;
    const int n = nrows[b];
    const int t = threadIdx.x;
    const int r = blockIdx.x*4 + (t >> 7);
    const int c = (t & 127) * 4;
    float s = rp9[((size_t)b*NSP + 0)*N + r]
            + rp9[((size_t)b*NSP + 1)*N + r]
            + rp9[((size_t)b*NSP + 2)*N + r]
            + rp9[((size_t)b*NSP + 3)*N + r];
    float ur = (r < n) ? 1.f / s : 0.f;
    float4 v = *(const float4*)(vf8 + b*N + c);
    const size_t off = (size_t)b*N*N + (size_t)r*N + c;
    float4 a = *(const float4*)(A + off);
    float4 o;
    o.x = (a.x + EPS) * ur * v.x;
    o.y = (a.y + EPS) * ur * v.y;
    o.z = (a.z + EPS) * ur * v.z;
    o.w = (a.w + EPS) * ur * v.w;
    *(float4*)(out + off) = o;
}

extern "C" void kernel_launch(void* const* d_in, const int* in_sizes, int n_in,
                              void* d_out, int out_size, void* d_ws, size_t ws_size,
                              hipStream_t stream) {
    const float* A     = (const float*)d_in[0];
    const int*   nrows = (const int*)d_in[1];
    float*       out   = (float*)d_out;
    const int    B     = in_sizes[1];   // 128

    float* rpA = (float*)d_ws;
    float* rpB = rpA + (size_t)B * NSP * N;
    float* vf8 = rpB + (size_t)B * NSP * N;
    // per-sample barrier counters: 1 cacheline (32 uints) per b, at +4 MiB.
    unsigned int* bar = (unsigned int*)((char*)d_ws + (4u << 20));

    // ---- preferred path: single cooperative kernel, 2 blocks/CU resident ----
    do {
        if (hipMemsetAsync(bar, 0, (size_t)B * 32 * sizeof(unsigned int),
                           stream) != hipSuccess) break;
        void* args[] = { (void*)&A, (void*)&nrows, (void*)&rpA, (void*)&rpB,
                         (void*)&out, (void*)&bar };
        hipError_t err = hipLaunchCooperativeKernel(
            reinterpret_cast<const void*>(&k_fused),
            dim3(NSP, B), dim3(512), args, 0, stream);
        if (err == hipSuccess) return;
    } while (0);

    // ---- fallback: previous verified multi-kernel pipeline ----
    size_t head = ((size_t)2*B*NSP*N + (size_t)B*N) * sizeof(float);
    size_t abf_bytes = (size_t)B * N * (N/2) * sizeof(unsigned int);
    unsigned int* Abf = (ws_size >= head + abf_bytes)
                      ? (unsigned int*)((char*)d_ws + head)
                      : (unsigned int*)d_out;

    hipFuncSetAttribute(reinterpret_cast<const void*>(k_pass0),
                        hipFuncAttributeMaxDynamicSharedMemorySize, LDS_BYTES);
    hipFuncSetAttribute(reinterpret_cast<const void*>(k_passN),
                        hipFuncAttributeMaxDynamicSharedMemorySize, LDS_BYTES);

    dim3 g(NSP, B);
    k_pass0<<<g, 512, LDS_BYTES, stream>>>(A, nrows, Abf, rpA);
    k_passN<<<g, 512, LDS_BYTES, stream>>>(Abf, nrows, rpA, rpB, nullptr);
    k_passN<<<g, 512, LDS_BYTES, stream>>>(Abf, nrows, rpB, rpA, nullptr);
    k_passN<<<g, 512, LDS_BYTES, stream>>>(Abf, nrows, rpA, rpB, nullptr);
    k_passN<<<g, 512, LDS_BYTES, stream>>>(Abf, nrows, rpB, rpA, vf8);
    k_epi<<<dim3(N/4, B), 512, 0, stream>>>(A, nrows, rpA, vf8, out);
}

// Round 6
// 289.787 us; speedup vs baseline: 4.6485x; 3.1572x over previous
//
#include <hip/hip_runtime.h>

#define N     512
#define NSP   4          // column stripes per sample
#define SC    128        // columns per stripe
#define EPS   1e-4f

// ---- fallback (previous pipeline) LDS layout ----
#define MROW  65
#define LDS_U   (512 * MROW + 512 + 128 * 33 + 128 + 64)
#define LDS_BYTES (LDS_U * 4)

// ---- f16 helpers ----
union U32H { unsigned int u; _Float16 h[2]; };
__device__ inline float h_lo(unsigned int x){ U32H t; t.u = x; return (float)t.h[0]; }
__device__ inline float h_hi(unsigned int x){ U32H t; t.u = x; return (float)t.h[1]; }
__device__ inline unsigned int h_pk(float a, float b){ U32H t; t.h[0]=(_Float16)a; t.h[1]=(_Float16)b; return t.u; }

typedef _Float16 half2v __attribute__((ext_vector_type(2)));
#if __has_builtin(__builtin_amdgcn_fdot2)
__device__ inline float dot2(unsigned int m, unsigned int v, float c){
    return __builtin_amdgcn_fdot2(__builtin_bit_cast(half2v, m), __builtin_bit_cast(half2v, v), c, false);
}
#else
__device__ inline float dot2(unsigned int m, unsigned int v, float c){
    return c + h_lo(m)*h_lo(v) + h_hi(m)*h_hi(v);
}
#endif

typedef unsigned int uint4v __attribute__((ext_vector_type(4)));

// agent-scope, fence-free communication primitives (bypass non-coherent L2)
__device__ inline void rp_store(float* p, float v){
    __hip_atomic_store(p, v, __ATOMIC_RELAXED, __HIP_MEMORY_SCOPE_AGENT);
}
__device__ inline float rp_load(float* p){
    return __hip_atomic_load(p, __ATOMIC_RELAXED, __HIP_MEMORY_SCOPE_AGENT);
}

// ============================================================================
// Fused cooperative kernel, take 6.
// CONFIRMED (r5): __launch_bounds__ 2nd arg = blocks/CU on this toolchain;
// (512,2) -> VGPR cap 128 -> m register-resident (VGPR=120, spills gone).
// r5 residual bottleneck: __threadfence() x2 per sync per block = 5120
// agent fences = per-XCD L2 writeback/invalidate storms (745us at 1.9% VALU),
// plus occupancy fell to 1 block/CU (VGPR at the 4-wave boundary).
// Fix: ZERO fences. rp exchanged via agent-scope RELAXED atomic store/load
// (write-through / L2-bypass by construction); arrive+poll via RELAXED RMW
// (visibility proven r5); per-wave s_waitcnt vmcnt(0) before the block
// barrier orders data before flag. LDS red/rowred unioned: 38.5 KB/block.
// Per-sample (4-block) barrier scope: deadlock-free under any residency.
// ============================================================================

#define SAMPLE_SYNC() do {                                                    \
    asm volatile("s_waitcnt vmcnt(0)" ::: "memory");                          \
    __syncthreads();                                                          \
    ++phase;                                                                  \
    if (t == 0) {                                                             \
        __hip_atomic_fetch_add(barb, 1u, __ATOMIC_RELAXED,                    \
                               __HIP_MEMORY_SCOPE_AGENT);                     \
        const unsigned int tgt_ = (unsigned int)(phase * NSP);                \
        while (__hip_atomic_fetch_add(barb, 0u, __ATOMIC_RELAXED,             \
                                      __HIP_MEMORY_SCOPE_AGENT) < tgt_) {     \
            __builtin_amdgcn_s_sleep(8);                                      \
        }                                                                     \
    }                                                                         \
    __syncthreads();                                                          \
} while (0)

// col-sum reduce across 32 row-partitions -> vf = 1/colsum, vpk = packed f16
// uses sh[0 .. 128*33) (disjoint in time from ROW_PART's use)
#define COL_REDUCE() do {                                                     \
    _Pragma("unroll")                                                         \
    for (int k_ = 0; k_ < 8; ++k_) sh[(8*j + k_)*33 + part] = acc[k_];        \
    __syncthreads();                                                          \
    if (t < 128) {                                                            \
        float s_ = 0.f;                                                       \
        _Pragma("unroll")                                                     \
        for (int p_ = 0; p_ < 32; ++p_) s_ += sh[t*33 + p_];                  \
        vf[t] = (c0 + t < n) ? 1.f / s_ : 0.f;                                \
    }                                                                         \
    __syncthreads();                                                          \
    if (t < 64) vpk[t] = h_pk(vf[2*t], vf[2*t+1]);                            \
    __syncthreads();                                                          \
} while (0)

// row partials: dot(m-row, v) per owned row -> sh -> sum over 16 j-lanes,
// publish via agent-scope atomic store (no fence needed)
#define ROW_PART(RPOUT) do {                                                  \
    const unsigned int vp0_ = vpk[4*j+0], vp1_ = vpk[4*j+1];                  \
    const unsigned int vp2_ = vpk[4*j+2], vp3_ = vpk[4*j+3];                  \
    _Pragma("unroll")                                                         \
    for (int it_ = 0; it_ < 16; ++it_) {                                      \
        float p_ = dot2(m[it_][0], vp0_, 0.f);                                \
        p_ = dot2(m[it_][1], vp1_, p_);                                       \
        p_ = dot2(m[it_][2], vp2_, p_);                                       \
        p_ = dot2(m[it_][3], vp3_, p_);                                       \
        sh[(it_*32 + part)*17 + j] = p_;                                      \
    }                                                                         \
    __syncthreads();                                                          \
    {                                                                         \
        float s_ = 0.f;                                                       \
        _Pragma("unroll")                                                     \
        for (int q_ = 0; q_ < 16; ++q_) s_ += sh[t*17 + q_];                  \
        rp_store((RPOUT) + rpOff + t, s_);                                    \
    }                                                                         \
    __syncthreads();                                                          \
} while (0)

__global__ __launch_bounds__(512, 2)
void k_fused(const float* __restrict__ A, const int* __restrict__ nrows,
             float* __restrict__ rpA, float* __restrict__ rpB,
             float* __restrict__ out, unsigned int* __restrict__ bar) {
    __shared__ float sh[512*17];         // 34.8 KiB (red & rowred, unioned)
    __shared__ float uu[512];
    __shared__ float vf[128];
    __shared__ unsigned int vpk[64];     // total ~37.6 KiB -> 2 blocks/CU easy

    const int b = blockIdx.y, sp = blockIdx.x, c0 = sp * SC;
    const int n = nrows[b];
    const int t = threadIdx.x;
    const int l = t & 63;
    const int j = l & 15;
    const int part = (t >> 6) * 4 + (l >> 4);   // 0..31
    const size_t baseA = (size_t)b * N * N;
    const int cb = c0 + 8*j;
    const size_t rpOff = ((size_t)b * NSP + sp) * N;
    const size_t rpB0  = (size_t)b * NSP * N;
    unsigned int* barb = bar + (size_t)b * 32;  // one cacheline per sample
    int phase = 0;

    uint4v m[16];            // must stay in VGPRs: constant indices only
    float acc[8];

    // ---- load A once -> masked f16 in registers; pass-0 col sums (u == 1) ----
    {
        bool cok0 = (cb+0) < n, cok1 = (cb+1) < n, cok2 = (cb+2) < n, cok3 = (cb+3) < n;
        bool cok4 = (cb+4) < n, cok5 = (cb+5) < n, cok6 = (cb+6) < n, cok7 = (cb+7) < n;
#pragma unroll
        for (int k = 0; k < 8; ++k) acc[k] = 0.f;
#pragma unroll
        for (int it = 0; it < 16; ++it) {
            const int r = it*32 + part;
            const float4* p = (const float4*)(A + baseA + (size_t)r*N + cb);
            float4 a0 = p[0], a1 = p[1];
            const bool rok = r < n;
            float e0 = (rok & cok0) ? a0.x + EPS : 0.f;
            float e1 = (rok & cok1) ? a0.y + EPS : 0.f;
            float e2 = (rok & cok2) ? a0.z + EPS : 0.f;
            float e3 = (rok & cok3) ? a0.w + EPS : 0.f;
            float e4 = (rok & cok4) ? a1.x + EPS : 0.f;
            float e5 = (rok & cok5) ? a1.y + EPS : 0.f;
            float e6 = (rok & cok6) ? a1.z + EPS : 0.f;
            float e7 = (rok & cok7) ? a1.w + EPS : 0.f;
            acc[0] += e0; acc[1] += e1; acc[2] += e2; acc[3] += e3;
            acc[4] += e4; acc[5] += e5; acc[6] += e6; acc[7] += e7;
            m[it][0] = h_pk(e0, e1);
            m[it][1] = h_pk(e2, e3);
            m[it][2] = h_pk(e4, e5);
            m[it][3] = h_pk(e6, e7);
        }
    }
    COL_REDUCE();            // v0
    ROW_PART(rpA);           // rp1
    SAMPLE_SYNC();

    // ---- passes 1..4: u = 1/sum(rp), col-normalize, next row partials ----
    float* rIn = rpA; float* rOut = rpB;
    for (int ps = 0; ps < 4; ++ps) {
        {
            float s = rp_load(rIn + rpB0 + 0*N + t) + rp_load(rIn + rpB0 + 1*N + t)
                    + rp_load(rIn + rpB0 + 2*N + t) + rp_load(rIn + rpB0 + 3*N + t);
            uu[t] = (t < n) ? 1.f / s : 0.f;
        }
        __syncthreads();
#pragma unroll
        for (int k = 0; k < 8; ++k) acc[k] = 0.f;
#pragma unroll
        for (int it = 0; it < 16; ++it) {
            const float ur = uu[it*32 + part];
            acc[0] += ur * h_lo(m[it][0]);
            acc[1] += ur * h_hi(m[it][0]);
            acc[2] += ur * h_lo(m[it][1]);
            acc[3] += ur * h_hi(m[it][1]);
            acc[4] += ur * h_lo(m[it][2]);
            acc[5] += ur * h_hi(m[it][2]);
            acc[6] += ur * h_lo(m[it][3]);
            acc[7] += ur * h_hi(m[it][3]);
        }
        COL_REDUCE();        // v2 / v4 / v6 / v8
        ROW_PART(rOut);      // rp3 / rp5 / rp7 / rp9
        SAMPLE_SYNC();
        float* tmp = rIn; rIn = rOut; rOut = tmp;
    }
    // after 4 swaps: rIn holds rp9; vf holds v8

    // ---- epilogue from registers: out = m * u9[r] * v8[c] ----
    {
        float s = rp_load(rIn + rpB0 + 0*N + t) + rp_load(rIn + rpB0 + 1*N + t)
                + rp_load(rIn + rpB0 + 2*N + t) + rp_load(rIn + rpB0 + 3*N + t);
        uu[t] = (t < n) ? 1.f / s : 0.f;
    }
    __syncthreads();
    const float v0 = vf[8*j+0], v1 = vf[8*j+1], v2 = vf[8*j+2], v3 = vf[8*j+3];
    const float v4 = vf[8*j+4], v5 = vf[8*j+5], v6 = vf[8*j+6], v7 = vf[8*j+7];
#pragma unroll
    for (int it = 0; it < 16; ++it) {
        const int r = it*32 + part;
        const float ur = uu[r];
        float4 o0, o1;
        o0.x = h_lo(m[it][0]) * ur * v0;
        o0.y = h_hi(m[it][0]) * ur * v1;
        o0.z = h_lo(m[it][1]) * ur * v2;
        o0.w = h_hi(m[it][1]) * ur * v3;
        o1.x = h_lo(m[it][2]) * ur * v4;
        o1.y = h_hi(m[it][2]) * ur * v5;
        o1.z = h_lo(m[it][3]) * ur * v6;
        o1.w = h_hi(m[it][3]) * ur * v7;
        float4* q = (float4*)(out + baseA + (size_t)r*N + cb);
        q[0] = o0; q[1] = o1;
    }
}

// ============================================================================
// Fallback: verified 6-kernel pipeline (runs if cooperative launch or the
// barrier-counter memset is rejected).
// ============================================================================

__device__ inline void pass_tail(unsigned int* M2, float* red, float* vf, unsigned int* vpk,
                                 const float acc[8], int t, int part, int j, int c0, int n,
                                 int b, int sp, float* __restrict__ rp_out,
                                 float* __restrict__ vf_out) {
#pragma unroll
    for (int k = 0; k < 8; ++k) red[(8*j + k)*33 + part] = acc[k];
    __syncthreads();
    if (t < 128) {
        float s = 0.f;
#pragma unroll
        for (int p = 0; p < 32; ++p) s += red[t*33 + p];
        float v = (c0 + t < n) ? 1.f / s : 0.f;
        vf[t] = v;
        if (vf_out) vf_out[b*N + c0 + t] = v;
    }
    __syncthreads();
    if (t < 64) vpk[t] = h_pk(vf[2*t], vf[2*t+1]);
    __syncthreads();
    float p = 0.f;
    const unsigned int* row = M2 + t * MROW;
#pragma unroll
    for (int q = 0; q < 64; ++q) p = dot2(row[q], vpk[q], p);
    rp_out[((size_t)b*NSP + sp)*N + t] = p;
}

__global__ __launch_bounds__(512)
void k_pass0(const float* __restrict__ A, const int* __restrict__ nrows,
             unsigned int* __restrict__ Abf, float* __restrict__ rp_out) {
    extern __shared__ unsigned int lds[];
    unsigned int* M2 = lds;
    float* uu = (float*)(lds + 512*MROW);
    float* red = uu + 512;
    float* vf  = red + 128*33;
    unsigned int* vpk = (unsigned int*)(vf + 128);

    const int b = blockIdx.y, sp = blockIdx.x, c0 = sp * SC;
    const int n = nrows[b];
    const int t = threadIdx.x;
    const int w = t >> 6, l = t & 63;
    const int j = l & 15, rg = l >> 4;
    const size_t baseA = (size_t)b * N * N;
    const size_t baseH = (size_t)b * N * (N/2);
    const int cb = c0 + 8*j;

    bool cok[8];
#pragma unroll
    for (int k = 0; k < 8; ++k) cok[k] = (cb + k) < n;

    float acc[8] = {0,0,0,0,0,0,0,0};
    for (int it = 0; it < 16; ++it) {
        int r = it*32 + w*4 + rg;
        const float4* p = (const float4*)(A + baseA + (size_t)r*N + cb);
        float4 a0 = p[0], a1 = p[1];
        bool rok = r < n;
        float e[8];
        e[0] = (rok && cok[0]) ? a0.x + EPS : 0.f;
        e[1] = (rok && cok[1]) ? a0.y + EPS : 0.f;
        e[2] = (rok && cok[2]) ? a0.z + EPS : 0.f;
        e[3] = (rok && cok[3]) ? a0.w + EPS : 0.f;
        e[4] = (rok && cok[4]) ? a1.x + EPS : 0.f;
        e[5] = (rok && cok[5]) ? a1.y + EPS : 0.f;
        e[6] = (rok && cok[6]) ? a1.z + EPS : 0.f;
        e[7] = (rok && cok[7]) ? a1.w + EPS : 0.f;
#pragma unroll
        for (int k = 0; k < 8; ++k) acc[k] += e[k];
        uint4 q;
        q.x = h_pk(e[0], e[1]); q.y = h_pk(e[2], e[3]);
        q.z = h_pk(e[4], e[5]); q.w = h_pk(e[6], e[7]);
        *(uint4*)(Abf + baseH + (size_t)r*(N/2) + c0/2 + 4*j) = q;
        unsigned int* dst = M2 + r*MROW + 4*j;
        dst[0] = q.x; dst[1] = q.y; dst[2] = q.z; dst[3] = q.w;
    }
    (void)uu;
    pass_tail(M2, red, vf, vpk, acc, t, w*4 + rg, j, c0, n, b, sp, rp_out, nullptr);
}

__global__ __launch_bounds__(512)
void k_passN(const unsigned int* __restrict__ Abf, const int* __restrict__ nrows,
             const float* __restrict__ rp_in, float* __restrict__ rp_out,
             float* __restrict__ vf_out) {
    extern __shared__ unsigned int lds[];
    unsigned int* M2 = lds;
    float* uu = (float*)(lds + 512*MROW);
    float* red = uu + 512;
    float* vf  = red + 128*33;
    unsigned int* vpk = (unsigned int*)(vf + 128);

    const int b = blockIdx.y, sp = blockIdx.x, c0 = sp * SC;
    const int n = nrows[b];
    const int t = threadIdx.x;
    const int w = t >> 6, l = t & 63;
    const int j = l & 15, rg = l >> 4;
    const size_t baseH = (size_t)b * N * (N/2);

    {
        float s = rp_in[((size_t)b*NSP + 0)*N + t]
                + rp_in[((size_t)b*NSP + 1)*N + t]
                + rp_in[((size_t)b*NSP + 2)*N + t]
                + rp_in[((size_t)b*NSP + 3)*N + t];
        uu[t] = (t < n) ? 1.f / s : 0.f;
    }
    __syncthreads();

    float acc[8] = {0,0,0,0,0,0,0,0};
    for (int it = 0; it < 16; ++it) {
        int r = it*32 + w*4 + rg;
        uint4 q = *(const uint4*)(Abf + baseH + (size_t)r*(N/2) + c0/2 + 4*j);
        float ur = uu[r];
        acc[0] += ur * h_lo(q.x); acc[1] += ur * h_hi(q.x);
        acc[2] += ur * h_lo(q.y); acc[3] += ur * h_hi(q.y);
        acc[4] += ur * h_lo(q.z); acc[5] += ur * h_hi(q.z);
        acc[6] += ur * h_lo(q.w); acc[7] += ur * h_hi(q.w);
        unsigned int* dst = M2 + r*MROW + 4*j;
        dst[0] = q.x; dst[1] = q.y; dst[2] = q.z; dst[3] = q.w;
    }
    __syncthreads();
    pass_tail(M2, red, vf, vpk, acc, t, w*4 + rg, j, c0, n, b, sp, rp_out, vf_out);
}

__global__ __launch_bounds__(512)
void k_epi(const float* __restrict__ A, const int* __restrict__ nrows,
           const float* __restrict__ rp9, const float* __restrict__ vf8,
           float* __restrict__ out) {
    const int b = blockIdx.y;
    const int n = nrows[b];
    const int t = threadIdx.x;
    const int r = blockIdx.x*4 + (t >> 7);
    const int c = (t & 127) * 4;
    float s = rp9[((size_t)b*NSP + 0)*N + r]
            + rp9[((size_t)b*NSP + 1)*N + r]
            + rp9[((size_t)b*NSP + 2)*N + r]
            + rp9[((size_t)b*NSP + 3)*N + r];
    float ur = (r < n) ? 1.f / s : 0.f;
    float4 v = *(const float4*)(vf8 + b*N + c);
    const size_t off = (size_t)b*N*N + (size_t)r*N + c;
    float4 a = *(const float4*)(A + off);
    float4 o;
    o.x = (a.x + EPS) * ur * v.x;
    o.y = (a.y + EPS) * ur * v.y;
    o.z = (a.z + EPS) * ur * v.z;
    o.w = (a.w + EPS) * ur * v.w;
    *(float4*)(out + off) = o;
}

extern "C" void kernel_launch(void* const* d_in, const int* in_sizes, int n_in,
                              void* d_out, int out_size, void* d_ws, size_t ws_size,
                              hipStream_t stream) {
    const float* A     = (const float*)d_in[0];
    const int*   nrows = (const int*)d_in[1];
    float*       out   = (float*)d_out;
    const int    B     = in_sizes[1];   // 128

    float* rpA = (float*)d_ws;
    float* rpB = rpA + (size_t)B * NSP * N;
    float* vf8 = rpB + (size_t)B * NSP * N;
    // per-sample barrier counters: 1 cacheline (32 uints) per b, at +4 MiB.
    unsigned int* bar = (unsigned int*)((char*)d_ws + (4u << 20));

    // ---- preferred path: single cooperative kernel, 2 blocks/CU resident ----
    do {
        if (hipMemsetAsync(bar, 0, (size_t)B * 32 * sizeof(unsigned int),
                           stream) != hipSuccess) break;
        void* args[] = { (void*)&A, (void*)&nrows, (void*)&rpA, (void*)&rpB,
                         (void*)&out, (void*)&bar };
        hipError_t err = hipLaunchCooperativeKernel(
            reinterpret_cast<const void*>(&k_fused),
            dim3(NSP, B), dim3(512), args, 0, stream);
        if (err == hipSuccess) return;
    } while (0);

    // ---- fallback: previous verified multi-kernel pipeline ----
    size_t head = ((size_t)2*B*NSP*N + (size_t)B*N) * sizeof(float);
    size_t abf_bytes = (size_t)B * N * (N/2) * sizeof(unsigned int);
    unsigned int* Abf = (ws_size >= head + abf_bytes)
                      ? (unsigned int*)((char*)d_ws + head)
                      : (unsigned int*)d_out;

    hipFuncSetAttribute(reinterpret_cast<const void*>(k_pass0),
                        hipFuncAttributeMaxDynamicSharedMemorySize, LDS_BYTES);
    hipFuncSetAttribute(reinterpret_cast<const void*>(k_passN),
                        hipFuncAttributeMaxDynamicSharedMemorySize, LDS_BYTES);

    dim3 g(NSP, B);
    k_pass0<<<g, 512, LDS_BYTES, stream>>>(A, nrows, Abf, rpA);
    k_passN<<<g, 512, LDS_BYTES, stream>>>(Abf, nrows, rpA, rpB, nullptr);
    k_passN<<<g, 512, LDS_BYTES, stream>>>(Abf, nrows, rpB, rpA, nullptr);
    k_passN<<<g, 512, LDS_BYTES, stream>>>(Abf, nrows, rpA, rpB, nullptr);
    k_passN<<<g, 512, LDS_BYTES, stream>>>(Abf, nrows, rpB, rpA, vf8);
    k_epi<<<dim3(N/4, B), 512, 0, stream>>>(A, nrows, rpA, vf8, out);
}

// Round 7
// 269.005 us; speedup vs baseline: 5.0076x; 1.0773x over previous
//
#include <hip/hip_runtime.h>

#define N     512
#define NSP   4          // column stripes per sample
#define SC    128        // columns per stripe
#define EPS   1e-4f

// ---- f16 helpers ----
union U32H { unsigned int u; _Float16 h[2]; };
__device__ inline float h_lo(unsigned int x){ U32H t; t.u = x; return (float)t.h[0]; }
__device__ inline float h_hi(unsigned int x){ U32H t; t.u = x; return (float)t.h[1]; }
__device__ inline unsigned int h_pk(float a, float b){ U32H t; t.h[0]=(_Float16)a; t.h[1]=(_Float16)b; return t.u; }

typedef _Float16 half2v __attribute__((ext_vector_type(2)));
#if __has_builtin(__builtin_amdgcn_fdot2)
__device__ inline float dot2(unsigned int m, unsigned int v, float c){
    return __builtin_amdgcn_fdot2(__builtin_bit_cast(half2v, m), __builtin_bit_cast(half2v, v), c, false);
}
#else
__device__ inline float dot2(unsigned int m, unsigned int v, float c){
    return c + h_lo(m)*h_lo(v) + h_hi(m)*h_hi(v);
}
#endif

typedef unsigned int uint4v __attribute__((ext_vector_type(4)));

// agent-scope, fence-free communication primitives (bypass non-coherent L2)
__device__ inline void rp_store(float* p, float v){
    __hip_atomic_store(p, v, __ATOMIC_RELAXED, __HIP_MEMORY_SCOPE_AGENT);
}
__device__ inline float rp_load(float* p){
    return __hip_atomic_load(p, __ATOMIC_RELAXED, __HIP_MEMORY_SCOPE_AGENT);
}

// ============================================================================
// Fused kernel, take 7 — PLAIN launch (cooperative dispatch path measured at
// ~120-180us fixed overhead across r1/r3/r5/r6; kernel itself is 108us).
// Correctness without cooperative guarantee: barrier is per-sample (4 blocks).
// Block swizzle g=(s*4+k)*8+c puts sample b=(s<<3|c)'s 4 blocks at linear IDs
// spaced 8 apart -> (a) first 32 dispatched blocks contain a complete sample,
// so in-order dispatch can never deadlock (finished samples free slots);
// (b) if XCD = linear%8, all 4 blocks of a sample share one XCD's L2.
// Residency: LDS 37.9KB -> 4/CU cap, VGPR 120 -> 2/CU; grid 512 = 256CUx2.
// Confirmed r5/r6: __launch_bounds__ 2nd arg = blocks/CU here; (512,2) gives
// the 128-VGPR cap that keeps m[16] register-resident (VGPR_Count=120).
// Fence-free sync (r6, confirmed): rp via agent-scope RELAXED atomics,
// barrier arrive/poll via RELAXED RMW, s_waitcnt vmcnt(0) before arrive.
// ============================================================================

#define SAMPLE_SYNC() do {                                                    \
    asm volatile("s_waitcnt vmcnt(0)" ::: "memory");                          \
    __syncthreads();                                                          \
    ++phase;                                                                  \
    if (t == 0) {                                                             \
        __hip_atomic_fetch_add(barb, 1u, __ATOMIC_RELAXED,                    \
                               __HIP_MEMORY_SCOPE_AGENT);                     \
        const unsigned int tgt_ = (unsigned int)(phase * NSP);                \
        while (__hip_atomic_fetch_add(barb, 0u, __ATOMIC_RELAXED,             \
                                      __HIP_MEMORY_SCOPE_AGENT) < tgt_) {     \
            __builtin_amdgcn_s_sleep(2);                                      \
        }                                                                     \
    }                                                                         \
    __syncthreads();                                                          \
} while (0)

// col-sum reduce across 32 row-partitions -> vf = 1/colsum, vpk = packed f16
#define COL_REDUCE() do {                                                     \
    _Pragma("unroll")                                                         \
    for (int k_ = 0; k_ < 8; ++k_) sh[(8*j + k_)*33 + part] = acc[k_];        \
    __syncthreads();                                                          \
    if (t < 128) {                                                            \
        float s_ = 0.f;                                                       \
        _Pragma("unroll")                                                     \
        for (int p_ = 0; p_ < 32; ++p_) s_ += sh[t*33 + p_];                  \
        vf[t] = (c0 + t < n) ? 1.f / s_ : 0.f;                                \
    }                                                                         \
    __syncthreads();                                                          \
    if (t < 64) vpk[t] = h_pk(vf[2*t], vf[2*t+1]);                            \
    __syncthreads();                                                          \
} while (0)

// row partials: dot(m-row, v) per owned row -> sh -> sum over 16 j-lanes,
// publish via agent-scope atomic store (no fence needed)
#define ROW_PART(RPOUT) do {                                                  \
    const unsigned int vp0_ = vpk[4*j+0], vp1_ = vpk[4*j+1];                  \
    const unsigned int vp2_ = vpk[4*j+2], vp3_ = vpk[4*j+3];                  \
    _Pragma("unroll")                                                         \
    for (int it_ = 0; it_ < 16; ++it_) {                                      \
        float p_ = dot2(m[it_][0], vp0_, 0.f);                                \
        p_ = dot2(m[it_][1], vp1_, p_);                                       \
        p_ = dot2(m[it_][2], vp2_, p_);                                       \
        p_ = dot2(m[it_][3], vp3_, p_);                                       \
        sh[(it_*32 + part)*17 + j] = p_;                                      \
    }                                                                         \
    __syncthreads();                                                          \
    {                                                                         \
        float s_ = 0.f;                                                       \
        _Pragma("unroll")                                                     \
        for (int q_ = 0; q_ < 16; ++q_) s_ += sh[t*17 + q_];                  \
        rp_store((RPOUT) + rpOff + t, s_);                                    \
    }                                                                         \
    __syncthreads();                                                          \
} while (0)

__global__ __launch_bounds__(512, 2)
void k_fused(const float* __restrict__ A, const int* __restrict__ nrows,
             float* __restrict__ rpA, float* __restrict__ rpB,
             float* __restrict__ out, unsigned int* __restrict__ bar) {
    __shared__ float sh[512*17];         // 34.8 KiB (red & rowred, unioned)
    __shared__ float uu[512];
    __shared__ float vf[128];
    __shared__ unsigned int vpk[64];     // total ~37.9 KiB

    // swizzled decode: g = (s*4+k)*8 + c  ->  b = s*8+c, sp = k
    const int g  = blockIdx.x;
    const int c_ = g & 7;
    const int q_ = g >> 3;
    const int sp = q_ & 3;
    const int b  = ((q_ >> 2) << 3) | c_;
    const int c0 = sp * SC;
    const int n = nrows[b];
    const int t = threadIdx.x;
    const int l = t & 63;
    const int j = l & 15;
    const int part = (t >> 6) * 4 + (l >> 4);   // 0..31
    const size_t baseA = (size_t)b * N * N;
    const int cb = c0 + 8*j;
    const size_t rpOff = ((size_t)b * NSP + sp) * N;
    const size_t rpB0  = (size_t)b * NSP * N;
    unsigned int* barb = bar + (size_t)b * 32;  // one cacheline per sample
    int phase = 0;

    uint4v m[16];            // must stay in VGPRs: constant indices only
    float acc[8];

    // ---- load A once -> masked f16 in registers; pass-0 col sums (u == 1) ----
    {
        bool cok0 = (cb+0) < n, cok1 = (cb+1) < n, cok2 = (cb+2) < n, cok3 = (cb+3) < n;
        bool cok4 = (cb+4) < n, cok5 = (cb+5) < n, cok6 = (cb+6) < n, cok7 = (cb+7) < n;
#pragma unroll
        for (int k = 0; k < 8; ++k) acc[k] = 0.f;
#pragma unroll
        for (int it = 0; it < 16; ++it) {
            const int r = it*32 + part;
            const float4* p = (const float4*)(A + baseA + (size_t)r*N + cb);
            float4 a0 = p[0], a1 = p[1];
            const bool rok = r < n;
            float e0 = (rok & cok0) ? a0.x + EPS : 0.f;
            float e1 = (rok & cok1) ? a0.y + EPS : 0.f;
            float e2 = (rok & cok2) ? a0.z + EPS : 0.f;
            float e3 = (rok & cok3) ? a0.w + EPS : 0.f;
            float e4 = (rok & cok4) ? a1.x + EPS : 0.f;
            float e5 = (rok & cok5) ? a1.y + EPS : 0.f;
            float e6 = (rok & cok6) ? a1.z + EPS : 0.f;
            float e7 = (rok & cok7) ? a1.w + EPS : 0.f;
            acc[0] += e0; acc[1] += e1; acc[2] += e2; acc[3] += e3;
            acc[4] += e4; acc[5] += e5; acc[6] += e6; acc[7] += e7;
            m[it][0] = h_pk(e0, e1);
            m[it][1] = h_pk(e2, e3);
            m[it][2] = h_pk(e4, e5);
            m[it][3] = h_pk(e6, e7);
        }
    }
    COL_REDUCE();            // v0
    ROW_PART(rpA);           // rp1
    SAMPLE_SYNC();

    // ---- passes 1..4: u = 1/sum(rp), col-normalize, next row partials ----
    float* rIn = rpA; float* rOut = rpB;
    for (int ps = 0; ps < 4; ++ps) {
        {
            float s = rp_load(rIn + rpB0 + 0*N + t) + rp_load(rIn + rpB0 + 1*N + t)
                    + rp_load(rIn + rpB0 + 2*N + t) + rp_load(rIn + rpB0 + 3*N + t);
            uu[t] = (t < n) ? 1.f / s : 0.f;
        }
        __syncthreads();
#pragma unroll
        for (int k = 0; k < 8; ++k) acc[k] = 0.f;
#pragma unroll
        for (int it = 0; it < 16; ++it) {
            const float ur = uu[it*32 + part];
            acc[0] += ur * h_lo(m[it][0]);
            acc[1] += ur * h_hi(m[it][0]);
            acc[2] += ur * h_lo(m[it][1]);
            acc[3] += ur * h_hi(m[it][1]);
            acc[4] += ur * h_lo(m[it][2]);
            acc[5] += ur * h_hi(m[it][2]);
            acc[6] += ur * h_lo(m[it][3]);
            acc[7] += ur * h_hi(m[it][3]);
        }
        COL_REDUCE();        // v2 / v4 / v6 / v8
        ROW_PART(rOut);      // rp3 / rp5 / rp7 / rp9
        SAMPLE_SYNC();
        float* tmp = rIn; rIn = rOut; rOut = tmp;
    }
    // after 4 swaps: rIn holds rp9; vf holds v8

    // ---- epilogue from registers: out = m * u9[r] * v8[c] ----
    {
        float s = rp_load(rIn + rpB0 + 0*N + t) + rp_load(rIn + rpB0 + 1*N + t)
                + rp_load(rIn + rpB0 + 2*N + t) + rp_load(rIn + rpB0 + 3*N + t);
        uu[t] = (t < n) ? 1.f / s : 0.f;
    }
    __syncthreads();
    const float v0 = vf[8*j+0], v1 = vf[8*j+1], v2 = vf[8*j+2], v3 = vf[8*j+3];
    const float v4 = vf[8*j+4], v5 = vf[8*j+5], v6 = vf[8*j+6], v7 = vf[8*j+7];
#pragma unroll
    for (int it = 0; it < 16; ++it) {
        const int r = it*32 + part;
        const float ur = uu[r];
        float4 o0, o1;
        o0.x = h_lo(m[it][0]) * ur * v0;
        o0.y = h_hi(m[it][0]) * ur * v1;
        o0.z = h_lo(m[it][1]) * ur * v2;
        o0.w = h_hi(m[it][1]) * ur * v3;
        o1.x = h_lo(m[it][2]) * ur * v4;
        o1.y = h_hi(m[it][2]) * ur * v5;
        o1.z = h_lo(m[it][3]) * ur * v6;
        o1.w = h_hi(m[it][3]) * ur * v7;
        float4* q = (float4*)(out + baseA + (size_t)r*N + cb);
        q[0] = o0; q[1] = o1;
    }
}

extern "C" void kernel_launch(void* const* d_in, const int* in_sizes, int n_in,
                              void* d_out, int out_size, void* d_ws, size_t ws_size,
                              hipStream_t stream) {
    const float* A     = (const float*)d_in[0];
    const int*   nrows = (const int*)d_in[1];
    float*       out   = (float*)d_out;
    const int    B     = in_sizes[1];   // 128

    float* rpA = (float*)d_ws;
    float* rpB = rpA + (size_t)B * NSP * N;
    // per-sample barrier counters: 1 cacheline (32 uints) per b, at +4 MiB.
    unsigned int* bar = (unsigned int*)((char*)d_ws + (4u << 20));

    hipMemsetAsync(bar, 0, (size_t)B * 32 * sizeof(unsigned int), stream);
    k_fused<<<dim3(NSP * B), dim3(512), 0, stream>>>(A, nrows, rpA, rpB, out, bar);
}